// Round 9
// baseline (321.399 us; speedup 1.0000x reference)
//
#include <hip/hip_runtime.h>
#include <hip/hip_bf16.h>
#include <math.h>

#define NN 50000
#define NE 625000
#define NG 256
#define CH 128
#define NPAD 50048

typedef __attribute__((ext_vector_type(8))) short short8;
typedef __attribute__((ext_vector_type(4))) float floatx4;

__device__ __forceinline__ float bf2f_lo(unsigned u) {
    union { unsigned i; float f; } c; c.i = u << 16; return c.f;
}
__device__ __forceinline__ float bf2f_hi(unsigned u) {
    union { unsigned i; float f; } c; c.i = u & 0xffff0000u; return c.f;
}
__device__ __forceinline__ float bfu2f(unsigned short us) {
    union { unsigned i; float f; } c; c.i = ((unsigned)us) << 16; return c.f;
}
__device__ __forceinline__ unsigned short f2bfu(float f) {
    __hip_bfloat16 b = __float2bfloat16(f);
    union { __hip_bfloat16 b; unsigned short u; } c; c.b = b; return c.u;
}

// ---------------- CSR build ----------------

__global__ __launch_bounds__(256) void k_hist(const int* __restrict__ dst, int* __restrict__ counts, int n) {
    int e = blockIdx.x * 256 + threadIdx.x;
    if (e < n) atomicAdd(&counts[dst[e]], 1);
}

__global__ __launch_bounds__(256) void k_scan1(const int* __restrict__ counts, int* __restrict__ partial, int n) {
    __shared__ int s[256];
    int t = threadIdx.x;
    int i = blockIdx.x * 256 + t;
    s[t] = (i < n) ? counts[i] : 0;
    __syncthreads();
    for (int d = 128; d > 0; d >>= 1) {
        if (t < d) s[t] += s[t + d];
        __syncthreads();
    }
    if (t == 0) partial[blockIdx.x] = s[0];
}

__global__ __launch_bounds__(256) void k_scan2(const int* __restrict__ partial, int* __restrict__ blockoff, int nb) {
    __shared__ int s[256];
    int t = threadIdx.x;
    int v = (t < nb) ? partial[t] : 0;
    s[t] = v;
    __syncthreads();
    for (int d = 1; d < 256; d <<= 1) {
        int x = (t >= d) ? s[t - d] : 0;
        __syncthreads();
        s[t] += x;
        __syncthreads();
    }
    if (t < nb) blockoff[t] = s[t] - v;  // exclusive
}

__global__ __launch_bounds__(256) void k_scan3(const int* __restrict__ counts, const int* __restrict__ blockoff,
                                               int* __restrict__ offsets, int n) {
    __shared__ int s[256];
    int t = threadIdx.x;
    int i = blockIdx.x * 256 + t;
    int v = (i < n) ? counts[i] : 0;
    s[t] = v;
    __syncthreads();
    for (int d = 1; d < 256; d <<= 1) {
        int x = (t >= d) ? s[t - d] : 0;
        __syncthreads();
        s[t] += x;
        __syncthreads();
    }
    if (i < n) offsets[i] = s[t] - v + blockoff[blockIdx.x];
}

__global__ __launch_bounds__(256) void k_fill(const int* __restrict__ src, const int* __restrict__ dst,
                                              const int* __restrict__ offsets, int* __restrict__ cursor,
                                              int* __restrict__ srclist, int n) {
    int e = blockIdx.x * 256 + threadIdx.x;
    if (e < n) {
        int d = dst[e];
        int pos = atomicAdd(&cursor[d], 1);
        srclist[offsets[d] + pos] = src[e];
    }
}

// ---------------- prep: fp32 -> bf16 conversions ----------------

__global__ __launch_bounds__(256) void k_prep_x(const float* __restrict__ x, unsigned short* __restrict__ hb, int n4) {
    int i = blockIdx.x * 256 + threadIdx.x;
    if (i < n4) {
        float4 v = *(const float4*)&x[i * 4];
        ushort4 o;
        o.x = f2bfu(v.x); o.y = f2bfu(v.y); o.z = f2bfu(v.z); o.w = f2bfu(v.w);
        *(ushort4*)&hb[i * 4] = o;
    }
}

// transpose+convert 9 conv weight mats: Wt[mat][n][k] = W[mat][k][n]
__global__ __launch_bounds__(256) void k_prep_w(const float* __restrict__ W, unsigned short* __restrict__ Wt, int total) {
    int i = blockIdx.x * 256 + threadIdx.x;
    if (i < total) {
        int mat = i >> 14;
        int rem = i & 16383;
        int k = rem >> 7;
        int n = rem & 127;
        Wt[mat * 16384 + n * 128 + k] = f2bfu(W[i]);
    }
}

// ---------------- aggregation (bf16): out[n] = h[n] + sum_{e: dst=n} h[src(e)] ----------------
// ONE NODE PER WAVE: 64 lanes x 2 channels (4B/lane). Per-wave trip count =
// the node's own degree -> zero divergence waste (vs max-of-4 with 16
// lanes/node). node is wave-uniform (readfirstlane) -> offsets/counts/srclist
// become scalar s_loads; row address = SGPR base + lane*4.

__global__ __launch_bounds__(256) void k_gather(const unsigned short* __restrict__ h, const int* __restrict__ srclist,
                                                const int* __restrict__ offsets, const int* __restrict__ counts,
                                                unsigned short* __restrict__ outb) {
    int t = threadIdx.x;
    int node = __builtin_amdgcn_readfirstlane(blockIdx.x * 4 + (t >> 6));
    int lane = t & 63;

    int off = offsets[node];
    int deg = counts[node];

    const unsigned* h32 = (const unsigned*)h;   // 2 bf16 per uint; row = 64 uints
    unsigned* o32 = (unsigned*)outb;

    float a0, a1;
    {
        unsigned v = h32[(size_t)node * 64 + lane];
        a0 = bf2f_lo(v); a1 = bf2f_hi(v);
    }
    int i = 0;
    for (; i + 3 < deg; i += 4) {
        int i0 = srclist[off + i + 0];
        int i1 = srclist[off + i + 1];
        int i2 = srclist[off + i + 2];
        int i3 = srclist[off + i + 3];
        unsigned v0 = h32[(size_t)i0 * 64 + lane];
        unsigned v1 = h32[(size_t)i1 * 64 + lane];
        unsigned v2 = h32[(size_t)i2 * 64 + lane];
        unsigned v3 = h32[(size_t)i3 * 64 + lane];
        a0 += bf2f_lo(v0); a1 += bf2f_hi(v0);
        a0 += bf2f_lo(v1); a1 += bf2f_hi(v1);
        a0 += bf2f_lo(v2); a1 += bf2f_hi(v2);
        a0 += bf2f_lo(v3); a1 += bf2f_hi(v3);
    }
    for (; i < deg; i++) {
        int i0 = srclist[off + i];
        unsigned v0 = h32[(size_t)i0 * 64 + lane];
        a0 += bf2f_lo(v0); a1 += bf2f_hi(v0);
    }
    unsigned short u0 = f2bfu(a0), u1 = f2bfu(a1);
    o32[(size_t)node * 64 + lane] = ((unsigned)u1 << 16) | (unsigned)u0;
}

// ---------------- fused 3-stage GIN MLP layer (bf16 MFMA), 128-node tile ----------------
// Best measured structure: 391 blocks, 256 threads = 4 waves 2x2,
// wave tile m64 x n64, two 32 KB LDS buffers ping-pong, 1 barrier per stage.
// poolMode: run-length segment-sum over sorted gid -> few atomics.

__global__ __launch_bounds__(256, 2) void k_layer(const unsigned short* __restrict__ A,
                                                  const unsigned short* __restrict__ Wt3,
                                                  const float* __restrict__ bias3,
                                                  unsigned short* __restrict__ outb,
                                                  float* __restrict__ pooled,
                                                  const int* __restrict__ gid,
                                                  int nrows, int poolMode) {
    __shared__ unsigned short buf[2][128 * 128];  // 2 x 32 KB

    int t = threadIdx.x;
    int wave = t >> 6;
    int lane = t & 63;
    int q = lane >> 4;
    int ml = lane & 15;
    int waveM = (wave >> 1) * 64;  // ch_out half
    int waveN = (wave & 1) * 64;   // node half
    int rowBase = blockIdx.x * 128;

    // stage in: [128 nodes][128 ch] -> XOR-swizzled LDS (16B chunk ^ node&15)
#pragma unroll
    for (int iter = 0; iter < 8; iter++) {
        int fid = t + iter * 256;
        int row = fid >> 4;
        int c = fid & 15;
        int r = rowBase + row;
        if (r >= nrows) r = nrows - 1;
        uint4 v = *(const uint4*)&A[(size_t)r * CH + c * 8];
        *(uint4*)&buf[0][row * 128 + ((c ^ (row & 15)) << 3)] = v;
    }
    __syncthreads();

    int rd = 0;
    for (int st = 0; st < 3; st++) {
        const unsigned short* Wm = Wt3 + st * 16384;
        const float* bs = bias3 + st * 128;

        floatx4 acc[4][4];
#pragma unroll
        for (int mt = 0; mt < 4; mt++)
#pragma unroll
            for (int nt = 0; nt < 4; nt++) acc[mt][nt] = (floatx4){0.f, 0.f, 0.f, 0.f};

#pragma unroll
        for (int s = 0; s < 4; s++) {
            short8 a[4], b[4];
#pragma unroll
            for (int mt = 0; mt < 4; mt++) {
                int m = waveM + mt * 16 + ml;
                a[mt] = *(const short8*)&Wm[m * 128 + s * 32 + q * 8];
            }
#pragma unroll
            for (int nt = 0; nt < 4; nt++) {
                int node = waveN + nt * 16 + ml;
                b[nt] = *(const short8*)&buf[rd][node * 128 + (((4 * s + q) ^ ml) << 3)];
            }
#pragma unroll
            for (int mt = 0; mt < 4; mt++)
#pragma unroll
                for (int nt = 0; nt < 4; nt++)
                    acc[mt][nt] = __builtin_amdgcn_mfma_f32_16x16x32_bf16(a[mt], b[nt], acc[mt][nt], 0, 0, 0);
        }

        int wr = rd ^ 1;
        int relu = (st < 2);
        int cw_base = (waveM >> 3);  // chunk base from ch_out half
#pragma unroll
        for (int mt = 0; mt < 4; mt++) {
            float4 bv = *(const float4*)&bs[waveM + mt * 16 + q * 4];
            float bva[4] = {bv.x, bv.y, bv.z, bv.w};
#pragma unroll
            for (int nt = 0; nt < 4; nt++) {
                int node = waveN + nt * 16 + ml;
                ushort4 o;
                float v0 = acc[mt][nt][0] + bva[0];
                float v1 = acc[mt][nt][1] + bva[1];
                float v2 = acc[mt][nt][2] + bva[2];
                float v3 = acc[mt][nt][3] + bva[3];
                if (relu) {
                    v0 = v0 > 0.f ? v0 : 0.f;
                    v1 = v1 > 0.f ? v1 : 0.f;
                    v2 = v2 > 0.f ? v2 : 0.f;
                    v3 = v3 > 0.f ? v3 : 0.f;
                }
                o.x = f2bfu(v0); o.y = f2bfu(v1); o.z = f2bfu(v2); o.w = f2bfu(v3);
                int cw = (cw_base + 2 * mt + (q >> 1)) ^ ml;
                *(ushort4*)&buf[wr][node * 128 + (cw << 3) + (q & 1) * 4] = o;
            }
        }
        __syncthreads();
        rd = wr;
    }

    if (!poolMode) {
        // coalesced copy-out: LDS (swizzled) -> global bf16 [node][ch]
#pragma unroll
        for (int iter = 0; iter < 8; iter++) {
            int fid = t + iter * 256;
            int row = fid >> 4;
            int c = fid & 15;
            int r = rowBase + row;
            if (r < nrows) {
                uint4 v = *(const uint4*)&buf[rd][row * 128 + ((c ^ (row & 15)) << 3)];
                *(uint4*)&outb[(size_t)r * CH + c * 8] = v;
            }
        }
    } else {
        // fused pool: run-length sum over sorted gid, one atomic per run
        int c = t & 127;
        int half = t >> 7;
        int n0 = half * 64;
        float runsum = 0.f;
        int curg = -1;
        for (int n = n0; n < n0 + 64; n++) {
            int r = rowBase + n;
            if (r >= nrows) break;
            int g = gid[r];
            unsigned short u = buf[rd][n * 128 + ((((c >> 3) ^ (n & 15))) << 3) + (c & 7)];
            float v = bfu2f(u);
            if (g != curg) {
                if (curg >= 0) atomicAdd(&pooled[(size_t)curg * CH + c], runsum);
                curg = g;
                runsum = 0.f;
            }
            runsum += v;
        }
        if (curg >= 0) atomicAdd(&pooled[(size_t)curg * CH + c], runsum);
    }
}

// ---------------- head: relu((pooled/cnt)@W1+b1) @ W2 + b2 -> softmax ----------------

__device__ int lowerb(const int* a, int n, int key) {
    int lo = 0, hi = n;
    while (lo < hi) {
        int mid = (lo + hi) >> 1;
        if (a[mid] < key) lo = mid + 1;
        else hi = mid;
    }
    return lo;
}

__global__ __launch_bounds__(128) void k_head(const float* __restrict__ pooled, const int* __restrict__ gid,
                                              const float* __restrict__ W1, const float* __restrict__ b1,
                                              const float* __restrict__ W2, const float* __restrict__ b2,
                                              float* __restrict__ out) {
    __shared__ float p[CH];
    __shared__ float h1[CH];
    __shared__ float lg[10];
    __shared__ int bounds[2];
    int b = blockIdx.x;
    int c = threadIdx.x;
    if (c == 0) bounds[0] = lowerb(gid, NN, b);
    if (c == 1) bounds[1] = lowerb(gid, NN, b + 1);
    __syncthreads();
    float cnt = (float)(bounds[1] - bounds[0]);
    if (cnt < 1.f) cnt = 1.f;
    p[c] = pooled[b * CH + c] / cnt;
    __syncthreads();
    float acc = b1[c];
    for (int k = 0; k < CH; k++) acc += p[k] * W1[k * CH + c];
    h1[c] = acc > 0.f ? acc : 0.f;
    __syncthreads();
    if (c < 10) {
        float a = b2[c];
        for (int k = 0; k < CH; k++) a += h1[k] * W2[k * 10 + c];
        lg[c] = a;
    }
    __syncthreads();
    if (c == 0) {
        float m = lg[0];
        for (int o = 1; o < 10; o++) m = fmaxf(m, lg[o]);
        float e[10];
        float s = 0.f;
        for (int o = 0; o < 10; o++) {
            e[o] = expf(lg[o] - m);
            s += e[o];
        }
        for (int o = 0; o < 10; o++) out[b * 10 + o] = e[o] / s;
    }
}

// ---------------- launch ----------------

extern "C" void kernel_launch(void* const* d_in, const int* in_sizes, int n_in,
                              void* d_out, int out_size, void* d_ws, size_t ws_size,
                              hipStream_t stream) {
    const float* x    = (const float*)d_in[0];
    const int* esrc   = (const int*)d_in[1];
    const int* edst   = (const int*)d_in[2];
    const int* gid    = (const int*)d_in[3];
    const float* convW = (const float*)d_in[4];
    const float* convb = (const float*)d_in[5];
    const float* d1W  = (const float*)d_in[6];
    const float* d1b  = (const float*)d_in[7];
    const float* d2W  = (const float*)d_in[8];
    const float* d2b  = (const float*)d_in[9];
    float* out = (float*)d_out;

    char* ws = (char*)d_ws;
    size_t off = 0;
    auto alloc = [&](size_t bytes) -> void* {
        void* p = ws + off;
        off += (bytes + 255) & ~(size_t)255;
        return p;
    };
    unsigned short* hb = (unsigned short*)alloc((size_t)NPAD * CH * 2);
    unsigned short* gb = (unsigned short*)alloc((size_t)NPAD * CH * 2);

    unsigned short* Wt = (unsigned short*)alloc((size_t)9 * 128 * 128 * 2);
    // counts and cursor adjacent -> one memset covers both
    int* counts   = (int*)alloc((size_t)NN * 4);
    int* cursor   = (int*)alloc((size_t)NN * 4);
    int* offs     = (int*)alloc((size_t)NN * 4);
    int* srclist  = (int*)alloc((size_t)NE * 4);
    int* partial  = (int*)alloc(256 * 4);
    int* blockoff = (int*)alloc(256 * 4);
    float* pooled = (float*)alloc((size_t)NG * CH * 4);

    size_t ccBytes = (size_t)((char*)offs - (char*)counts);
    hipMemsetAsync(counts, 0, ccBytes, stream);  // counts + cursor
    hipMemsetAsync(pooled, 0, (size_t)NG * CH * 4, stream);

    // CSR build
    k_hist<<<(NE + 255) / 256, 256, 0, stream>>>(edst, counts, NE);
    int nb = (NN + 255) / 256;  // 196
    k_scan1<<<nb, 256, 0, stream>>>(counts, partial, NN);
    k_scan2<<<1, 256, 0, stream>>>(partial, blockoff, nb);
    k_scan3<<<nb, 256, 0, stream>>>(counts, blockoff, offs, NN);
    k_fill<<<(NE + 255) / 256, 256, 0, stream>>>(esrc, edst, offs, cursor, srclist, NE);

    // prep: x -> bf16, conv weights -> bf16 transposed
    k_prep_x<<<(NN * CH / 4 + 255) / 256, 256, 0, stream>>>(x, hb, NN * CH / 4);
    k_prep_w<<<(9 * 128 * 128 + 255) / 256, 256, 0, stream>>>(convW, Wt, 9 * 128 * 128);

    int nblkL = (NN + 127) / 128;  // 391
    for (int l = 0; l < 3; l++) {
        k_gather<<<NN / 4, 256, 0, stream>>>(hb, srclist, offs, counts, gb);
        k_layer<<<nblkL, 256, 0, stream>>>(gb, Wt + (size_t)l * 3 * 16384, convb + l * 3 * CH,
                                           hb, pooled, gid, NN, (l == 2) ? 1 : 0);
    }
    k_head<<<NG, 128, 0, stream>>>(pooled, gid, d1W, d1b, d2W, d2b, out);
}

// Round 10
// 306.598 us; speedup vs baseline: 1.0483x; 1.0483x over previous
//
#include <hip/hip_runtime.h>
#include <hip/hip_bf16.h>
#include <math.h>

#define NN 50000
#define NE 625000
#define NG 256
#define CH 128
#define NPAD 50048

// k_setup grid partition
#define NB_HIST 2442   // ceil(625000/256)
#define NB_PX   6250   // 50000*128/4/256
#define NB_PW   576    // 9*128*128/256
#define NB_PZ   128    // 256*128/256

typedef __attribute__((ext_vector_type(8))) short short8;
typedef __attribute__((ext_vector_type(4))) float floatx4;

__device__ __forceinline__ float bf2f_lo(unsigned u) {
    union { unsigned i; float f; } c; c.i = u << 16; return c.f;
}
__device__ __forceinline__ float bf2f_hi(unsigned u) {
    union { unsigned i; float f; } c; c.i = u & 0xffff0000u; return c.f;
}
__device__ __forceinline__ float bfu2f(unsigned short us) {
    union { unsigned i; float f; } c; c.i = ((unsigned)us) << 16; return c.f;
}
__device__ __forceinline__ unsigned short f2bfu(float f) {
    __hip_bfloat16 b = __float2bfloat16(f);
    union { __hip_bfloat16 b; unsigned short u; } c; c.b = b; return c.u;
}

// ---------------- merged setup: hist + prep_x + prep_w + pooled-zero ----------------

__global__ __launch_bounds__(256) void k_setup(const int* __restrict__ edst, int* __restrict__ counts,
                                               const float* __restrict__ x, unsigned short* __restrict__ hb,
                                               const float* __restrict__ convW, unsigned short* __restrict__ Wt,
                                               float* __restrict__ pooled) {
    int b = blockIdx.x;
    int t = threadIdx.x;
    if (b < NB_HIST) {
        int e = b * 256 + t;
        if (e < NE) atomicAdd(&counts[edst[e]], 1);
    } else if (b < NB_HIST + NB_PX) {
        int i = (b - NB_HIST) * 256 + t;  // < 1,600,000 exactly
        float4 v = *(const float4*)&x[i * 4];
        ushort4 o;
        o.x = f2bfu(v.x); o.y = f2bfu(v.y); o.z = f2bfu(v.z); o.w = f2bfu(v.w);
        *(ushort4*)&hb[i * 4] = o;
    } else if (b < NB_HIST + NB_PX + NB_PW) {
        int i = (b - NB_HIST - NB_PX) * 256 + t;  // < 147456 exactly
        int mat = i >> 14;
        int rem = i & 16383;
        int k = rem >> 7;
        int n = rem & 127;
        Wt[mat * 16384 + n * 128 + k] = f2bfu(convW[i]);
    } else {
        int i = (b - NB_HIST - NB_PX - NB_PW) * 256 + t;  // < 32768 exactly
        pooled[i] = 0.f;
    }
}

// ---------------- CSR build (scans + fill) ----------------

__global__ __launch_bounds__(256) void k_scan1(const int* __restrict__ counts, int* __restrict__ partial, int n) {
    __shared__ int s[256];
    int t = threadIdx.x;
    int i = blockIdx.x * 256 + t;
    s[t] = (i < n) ? counts[i] : 0;
    __syncthreads();
    for (int d = 128; d > 0; d >>= 1) {
        if (t < d) s[t] += s[t + d];
        __syncthreads();
    }
    if (t == 0) partial[blockIdx.x] = s[0];
}

__global__ __launch_bounds__(256) void k_scan2(const int* __restrict__ partial, int* __restrict__ blockoff, int nb) {
    __shared__ int s[256];
    int t = threadIdx.x;
    int v = (t < nb) ? partial[t] : 0;
    s[t] = v;
    __syncthreads();
    for (int d = 1; d < 256; d <<= 1) {
        int x = (t >= d) ? s[t - d] : 0;
        __syncthreads();
        s[t] += x;
        __syncthreads();
    }
    if (t < nb) blockoff[t] = s[t] - v;  // exclusive
}

__global__ __launch_bounds__(256) void k_scan3(const int* __restrict__ counts, const int* __restrict__ blockoff,
                                               int* __restrict__ offsets, int n) {
    __shared__ int s[256];
    int t = threadIdx.x;
    int i = blockIdx.x * 256 + t;
    int v = (i < n) ? counts[i] : 0;
    s[t] = v;
    __syncthreads();
    for (int d = 1; d < 256; d <<= 1) {
        int x = (t >= d) ? s[t - d] : 0;
        __syncthreads();
        s[t] += x;
        __syncthreads();
    }
    if (i < n) offsets[i] = s[t] - v + blockoff[blockIdx.x];
}

__global__ __launch_bounds__(256) void k_fill(const int* __restrict__ src, const int* __restrict__ dst,
                                              const int* __restrict__ offsets, int* __restrict__ cursor,
                                              int* __restrict__ srclist, int n) {
    int e = blockIdx.x * 256 + threadIdx.x;
    if (e < n) {
        int d = dst[e];
        int pos = atomicAdd(&cursor[d], 1);
        srclist[offsets[d] + pos] = src[e];
    }
}

// ---------------- aggregation (bf16): out[n] = h[n] + sum_{e: dst=n} h[src(e)] ----------------
// Round-8 best: 16 lanes/node, 16 nodes per 256-thread block, unroll-4 with
// software-pipelined index prefetch.

__global__ __launch_bounds__(256) void k_gather(const unsigned short* __restrict__ h, const int* __restrict__ srclist,
                                                const int* __restrict__ offsets, const int* __restrict__ counts,
                                                unsigned short* __restrict__ outb) {
    int t = threadIdx.x;
    int node = blockIdx.x * 16 + (t >> 4);
    int sub = t & 15;
    int off = offsets[node];
    int deg = counts[node];

    float acc[8];
    {
        uint4 v = *(const uint4*)&h[(size_t)node * CH + sub * 8];
        acc[0] = bf2f_lo(v.x); acc[1] = bf2f_hi(v.x);
        acc[2] = bf2f_lo(v.y); acc[3] = bf2f_hi(v.y);
        acc[4] = bf2f_lo(v.z); acc[5] = bf2f_hi(v.z);
        acc[6] = bf2f_lo(v.w); acc[7] = bf2f_hi(v.w);
    }
#define ACC8(v) \
    acc[0] += bf2f_lo(v.x); acc[1] += bf2f_hi(v.x); \
    acc[2] += bf2f_lo(v.y); acc[3] += bf2f_hi(v.y); \
    acc[4] += bf2f_lo(v.z); acc[5] += bf2f_hi(v.z); \
    acc[6] += bf2f_lo(v.w); acc[7] += bf2f_hi(v.w);
    int i = 0;
    int i0 = 0, i1 = 0, i2 = 0, i3 = 0;
    if (i + 3 < deg) {
        i0 = srclist[off + 0]; i1 = srclist[off + 1];
        i2 = srclist[off + 2]; i3 = srclist[off + 3];
    }
    for (; i + 7 < deg; i += 4) {
        int j0 = srclist[off + i + 4];
        int j1 = srclist[off + i + 5];
        int j2 = srclist[off + i + 6];
        int j3 = srclist[off + i + 7];
        uint4 v0 = *(const uint4*)&h[(size_t)i0 * CH + sub * 8];
        uint4 v1 = *(const uint4*)&h[(size_t)i1 * CH + sub * 8];
        uint4 v2 = *(const uint4*)&h[(size_t)i2 * CH + sub * 8];
        uint4 v3 = *(const uint4*)&h[(size_t)i3 * CH + sub * 8];
        ACC8(v0) ACC8(v1) ACC8(v2) ACC8(v3)
        i0 = j0; i1 = j1; i2 = j2; i3 = j3;
    }
    if (i + 3 < deg) {
        uint4 v0 = *(const uint4*)&h[(size_t)i0 * CH + sub * 8];
        uint4 v1 = *(const uint4*)&h[(size_t)i1 * CH + sub * 8];
        uint4 v2 = *(const uint4*)&h[(size_t)i2 * CH + sub * 8];
        uint4 v3 = *(const uint4*)&h[(size_t)i3 * CH + sub * 8];
        ACC8(v0) ACC8(v1) ACC8(v2) ACC8(v3)
        i += 4;
    }
    for (; i < deg; i++) {
        uint4 v0 = *(const uint4*)&h[(size_t)srclist[off + i] * CH + sub * 8];
        ACC8(v0)
    }
#undef ACC8
    ushort4 o0, o1;
    o0.x = f2bfu(acc[0]); o0.y = f2bfu(acc[1]); o0.z = f2bfu(acc[2]); o0.w = f2bfu(acc[3]);
    o1.x = f2bfu(acc[4]); o1.y = f2bfu(acc[5]); o1.z = f2bfu(acc[6]); o1.w = f2bfu(acc[7]);
    *(ushort4*)&outb[(size_t)node * CH + sub * 8] = o0;
    *(ushort4*)&outb[(size_t)node * CH + sub * 8 + 4] = o1;
}

// ---------------- fused 3-stage GIN MLP layer (bf16 MFMA), 128-node tile ----------------
// Round-4/8 structure + cross-stage W prefetch: stage st+1's s=0 a-frags are
// issued before the epilogue/barrier of stage st (global loads fly across the
// barrier); the initial stage-0 frags are issued before the staging barrier.

__global__ __launch_bounds__(256, 2) void k_layer(const unsigned short* __restrict__ A,
                                                  const unsigned short* __restrict__ Wt3,
                                                  const float* __restrict__ bias3,
                                                  unsigned short* __restrict__ outb,
                                                  float* __restrict__ pooled,
                                                  const int* __restrict__ gid,
                                                  int nrows, int poolMode) {
    __shared__ unsigned short buf[2][128 * 128];  // 2 x 32 KB

    int t = threadIdx.x;
    int wave = t >> 6;
    int lane = t & 63;
    int q = lane >> 4;
    int ml = lane & 15;
    int waveM = (wave >> 1) * 64;  // ch_out half
    int waveN = (wave & 1) * 64;   // node half
    int rowBase = blockIdx.x * 128;

    // prefetch stage-0 s=0 W a-frags (overlap the staging barrier)
    short8 aPre[4];
#pragma unroll
    for (int mt = 0; mt < 4; mt++) {
        int m = waveM + mt * 16 + ml;
        aPre[mt] = *(const short8*)&Wt3[m * 128 + q * 8];
    }

    // stage in: [128 nodes][128 ch] -> XOR-swizzled LDS (16B chunk ^ node&15)
#pragma unroll
    for (int iter = 0; iter < 8; iter++) {
        int fid = t + iter * 256;
        int row = fid >> 4;
        int c = fid & 15;
        int r = rowBase + row;
        if (r >= nrows) r = nrows - 1;
        uint4 v = *(const uint4*)&A[(size_t)r * CH + c * 8];
        *(uint4*)&buf[0][row * 128 + ((c ^ (row & 15)) << 3)] = v;
    }
    __syncthreads();

    int rd = 0;
    for (int st = 0; st < 3; st++) {
        const unsigned short* Wm = Wt3 + st * 16384;
        const float* bs = bias3 + st * 128;

        floatx4 acc[4][4];
#pragma unroll
        for (int mt = 0; mt < 4; mt++)
#pragma unroll
            for (int nt = 0; nt < 4; nt++) acc[mt][nt] = (floatx4){0.f, 0.f, 0.f, 0.f};

#pragma unroll
        for (int s = 0; s < 4; s++) {
            short8 a[4], b[4];
#pragma unroll
            for (int mt = 0; mt < 4; mt++) {
                if (s == 0) {
                    a[mt] = aPre[mt];
                } else {
                    int m = waveM + mt * 16 + ml;
                    a[mt] = *(const short8*)&Wm[m * 128 + s * 32 + q * 8];
                }
            }
#pragma unroll
            for (int nt = 0; nt < 4; nt++) {
                int node = waveN + nt * 16 + ml;
                b[nt] = *(const short8*)&buf[rd][node * 128 + (((4 * s + q) ^ ml) << 3)];
            }
#pragma unroll
            for (int mt = 0; mt < 4; mt++)
#pragma unroll
                for (int nt = 0; nt < 4; nt++)
                    acc[mt][nt] = __builtin_amdgcn_mfma_f32_16x16x32_bf16(a[mt], b[nt], acc[mt][nt], 0, 0, 0);
        }

        // prefetch next stage's s=0 a-frags (issues before epilogue + barrier)
        if (st < 2) {
            const unsigned short* Wn = Wt3 + (st + 1) * 16384;
#pragma unroll
            for (int mt = 0; mt < 4; mt++) {
                int m = waveM + mt * 16 + ml;
                aPre[mt] = *(const short8*)&Wn[m * 128 + q * 8];
            }
        }

        int wr = rd ^ 1;
        int relu = (st < 2);
        int cw_base = (waveM >> 3);  // chunk base from ch_out half
#pragma unroll
        for (int mt = 0; mt < 4; mt++) {
            float4 bv = *(const float4*)&bs[waveM + mt * 16 + q * 4];
            float bva[4] = {bv.x, bv.y, bv.z, bv.w};
#pragma unroll
            for (int nt = 0; nt < 4; nt++) {
                int node = waveN + nt * 16 + ml;
                ushort4 o;
                float v0 = acc[mt][nt][0] + bva[0];
                float v1 = acc[mt][nt][1] + bva[1];
                float v2 = acc[mt][nt][2] + bva[2];
                float v3 = acc[mt][nt][3] + bva[3];
                if (relu) {
                    v0 = v0 > 0.f ? v0 : 0.f;
                    v1 = v1 > 0.f ? v1 : 0.f;
                    v2 = v2 > 0.f ? v2 : 0.f;
                    v3 = v3 > 0.f ? v3 : 0.f;
                }
                o.x = f2bfu(v0); o.y = f2bfu(v1); o.z = f2bfu(v2); o.w = f2bfu(v3);
                int cw = (cw_base + 2 * mt + (q >> 1)) ^ ml;
                *(ushort4*)&buf[wr][node * 128 + (cw << 3) + (q & 1) * 4] = o;
            }
        }
        __syncthreads();
        rd = wr;
    }

    if (!poolMode) {
        // coalesced copy-out: LDS (swizzled) -> global bf16 [node][ch]
#pragma unroll
        for (int iter = 0; iter < 8; iter++) {
            int fid = t + iter * 256;
            int row = fid >> 4;
            int c = fid & 15;
            int r = rowBase + row;
            if (r < nrows) {
                uint4 v = *(const uint4*)&buf[rd][row * 128 + ((c ^ (row & 15)) << 3)];
                *(uint4*)&outb[(size_t)r * CH + c * 8] = v;
            }
        }
    } else {
        // fused pool: run-length sum over sorted gid, one atomic per run
        int c = t & 127;
        int half = t >> 7;
        int n0 = half * 64;
        float runsum = 0.f;
        int curg = -1;
        for (int n = n0; n < n0 + 64; n++) {
            int r = rowBase + n;
            if (r >= nrows) break;
            int g = gid[r];
            unsigned short u = buf[rd][n * 128 + ((((c >> 3) ^ (n & 15))) << 3) + (c & 7)];
            float v = bfu2f(u);
            if (g != curg) {
                if (curg >= 0) atomicAdd(&pooled[(size_t)curg * CH + c], runsum);
                curg = g;
                runsum = 0.f;
            }
            runsum += v;
        }
        if (curg >= 0) atomicAdd(&pooled[(size_t)curg * CH + c], runsum);
    }
}

// ---------------- head: relu((pooled/cnt)@W1+b1) @ W2 + b2 -> softmax ----------------

__device__ int lowerb(const int* a, int n, int key) {
    int lo = 0, hi = n;
    while (lo < hi) {
        int mid = (lo + hi) >> 1;
        if (a[mid] < key) lo = mid + 1;
        else hi = mid;
    }
    return lo;
}

__global__ __launch_bounds__(128) void k_head(const float* __restrict__ pooled, const int* __restrict__ gid,
                                              const float* __restrict__ W1, const float* __restrict__ b1,
                                              const float* __restrict__ W2, const float* __restrict__ b2,
                                              float* __restrict__ out) {
    __shared__ float p[CH];
    __shared__ float h1[CH];
    __shared__ float lg[10];
    __shared__ int bounds[2];
    int b = blockIdx.x;
    int c = threadIdx.x;
    if (c == 0) bounds[0] = lowerb(gid, NN, b);
    if (c == 1) bounds[1] = lowerb(gid, NN, b + 1);
    __syncthreads();
    float cnt = (float)(bounds[1] - bounds[0]);
    if (cnt < 1.f) cnt = 1.f;
    p[c] = pooled[b * CH + c] / cnt;
    __syncthreads();
    float acc = b1[c];
    for (int k = 0; k < CH; k++) acc += p[k] * W1[k * CH + c];
    h1[c] = acc > 0.f ? acc : 0.f;
    __syncthreads();
    if (c < 10) {
        float a = b2[c];
        for (int k = 0; k < CH; k++) a += h1[k] * W2[k * 10 + c];
        lg[c] = a;
    }
    __syncthreads();
    if (c == 0) {
        float m = lg[0];
        for (int o = 1; o < 10; o++) m = fmaxf(m, lg[o]);
        float e[10];
        float s = 0.f;
        for (int o = 0; o < 10; o++) {
            e[o] = expf(lg[o] - m);
            s += e[o];
        }
        for (int o = 0; o < 10; o++) out[b * 10 + o] = e[o] / s;
    }
}

// ---------------- launch ----------------

extern "C" void kernel_launch(void* const* d_in, const int* in_sizes, int n_in,
                              void* d_out, int out_size, void* d_ws, size_t ws_size,
                              hipStream_t stream) {
    const float* x    = (const float*)d_in[0];
    const int* esrc   = (const int*)d_in[1];
    const int* edst   = (const int*)d_in[2];
    const int* gid    = (const int*)d_in[3];
    const float* convW = (const float*)d_in[4];
    const float* convb = (const float*)d_in[5];
    const float* d1W  = (const float*)d_in[6];
    const float* d1b  = (const float*)d_in[7];
    const float* d2W  = (const float*)d_in[8];
    const float* d2b  = (const float*)d_in[9];
    float* out = (float*)d_out;

    char* ws = (char*)d_ws;
    size_t off = 0;
    auto alloc = [&](size_t bytes) -> void* {
        void* p = ws + off;
        off += (bytes + 255) & ~(size_t)255;
        return p;
    };
    unsigned short* hb = (unsigned short*)alloc((size_t)NPAD * CH * 2);
    unsigned short* gb = (unsigned short*)alloc((size_t)NPAD * CH * 2);

    unsigned short* Wt = (unsigned short*)alloc((size_t)9 * 128 * 128 * 2);
    // counts and cursor adjacent -> one memset covers both
    int* counts   = (int*)alloc((size_t)NN * 4);
    int* cursor   = (int*)alloc((size_t)NN * 4);
    int* offs     = (int*)alloc((size_t)NN * 4);
    int* srclist  = (int*)alloc((size_t)NE * 4);
    int* partial  = (int*)alloc(256 * 4);
    int* blockoff = (int*)alloc(256 * 4);
    float* pooled = (float*)alloc((size_t)NG * CH * 4);

    size_t ccBytes = (size_t)((char*)offs - (char*)counts);
    hipMemsetAsync(counts, 0, ccBytes, stream);  // counts + cursor

    // merged setup: hist + x->bf16 + W transpose/convert + pooled zero
    k_setup<<<NB_HIST + NB_PX + NB_PW + NB_PZ, 256, 0, stream>>>(edst, counts, x, hb, convW, Wt, pooled);

    int nb = (NN + 255) / 256;  // 196
    k_scan1<<<nb, 256, 0, stream>>>(counts, partial, NN);
    k_scan2<<<1, 256, 0, stream>>>(partial, blockoff, nb);
    k_scan3<<<nb, 256, 0, stream>>>(counts, blockoff, offs, NN);
    k_fill<<<(NE + 255) / 256, 256, 0, stream>>>(esrc, edst, offs, cursor, srclist, NE);

    int nblkL = (NN + 127) / 128;  // 391
    for (int l = 0; l < 3; l++) {
        k_gather<<<NN / 16, 256, 0, stream>>>(hb, srclist, offs, counts, gb);
        k_layer<<<nblkL, 256, 0, stream>>>(gb, Wt + (size_t)l * 3 * 16384, convb + l * 3 * CH,
                                           hb, pooled, gid, NN, (l == 2) ? 1 : 0);
    }
    k_head<<<NG, 128, 0, stream>>>(pooled, gid, d1W, d1b, d2W, d2b, out);
}